// Round 1
// baseline (1061.773 us; speedup 1.0000x reference)
//
#include <hip/hip_runtime.h>
#include <hip/hip_bf16.h>

#define NB 32
#define LV 1000
#define LQ 1200
#define VD 128
#define HID 512
#define NH 8
#define HD 64
#define LP 200   // len_pro = 0.2 * 1000

__device__ __forceinline__ float bf2f(unsigned short u) {
    union { unsigned int ui; float f; } x; x.ui = ((unsigned int)u) << 16; return x.f;
}
__device__ __forceinline__ unsigned short f2bf(float f) {
    __hip_bfloat16 h = __float2bfloat16(f);
    return *reinterpret_cast<unsigned short*>(&h);
}

// ---------------------------------------------------------------------------
// K1: scores = max over 4 rows of att; top-200 by descending score (stable ->
// ties broken by ascending index, matching jnp.argsort(-scores)).
// Bitonic sort of 1024 (score, idx) pairs in LDS.
// ---------------------------------------------------------------------------
__global__ __launch_bounds__(256) void topk_kernel(const float* __restrict__ att,
                                                   int* __restrict__ idx_ws,
                                                   float* __restrict__ out_idx) {
    __shared__ float s[1024];
    __shared__ int   si[1024];
    int b = blockIdx.x, tid = threadIdx.x;
    for (int i = tid; i < 1024; i += 256) {
        float v = -INFINITY;
        if (i < LV) {
            const float* p = att + (size_t)b * 4 * LV + i;
            v = fmaxf(fmaxf(p[0], p[LV]), fmaxf(p[2 * LV], p[3 * LV]));
        }
        s[i] = v; si[i] = i;
    }
    __syncthreads();
    for (int k = 2; k <= 1024; k <<= 1) {
        for (int j = k >> 1; j > 0; j >>= 1) {
            for (int i = tid; i < 1024; i += 256) {
                int l = i ^ j;
                if (l > i) {
                    float a = s[i], c = s[l];
                    int ia = si[i], ic = si[l];
                    bool aFirst = (a > c) || (a == c && ia < ic); // a ranks before c
                    bool desc = ((i & k) == 0);
                    if (desc != aFirst) { s[i] = c; s[l] = a; si[i] = ic; si[l] = ia; }
                }
            }
            __syncthreads();
        }
    }
    for (int i = tid; i < LP; i += 256) {
        int v = si[i];
        idx_ws[b * LP + i]  = v;
        out_idx[b * LP + i] = (float)v;   // harness reads whole buffer as f32
    }
}

// ---------------------------------------------------------------------------
// K2: sinusoidal positional-encoding table pe[1200][128] (rows 0..199 reused
// for the gathered query since PE is applied post-selection).
// ---------------------------------------------------------------------------
__global__ __launch_bounds__(256) void pe_fill(float* __restrict__ pe) {
    int t = blockIdx.x * 256 + threadIdx.x;
    if (t >= LQ * VD) return;
    int r = t >> 7, c = t & 127;
    int i = c >> 1;
    float div = expf((float)(2 * i) * -0.07195578415606394f); // -ln(10000)/128
    float ang = (float)r * div;
    pe[t] = (c & 1) ? cosf(ang) : sinf(ang);
}

// ---------------------------------------------------------------------------
// K3: projection GEMM  dst[b, r, n] = bf16( (src[row]+pe?) @ W + bias )
// 128x128 tile, 8x8 per thread, k-chunk 32. A staged transposed ([k][r]),
// W is already k-major in gmem. fp32 compute, bf16 store.
// ---------------------------------------------------------------------------
template<int GATHER, int PE>
__global__ __launch_bounds__(256) void proj_kernel(
    const float* __restrict__ src, int srcRows,
    const int* __restrict__ idxws,
    const float* __restrict__ pe,
    const float* __restrict__ W, const float* __restrict__ bias,
    unsigned short* __restrict__ dst, int rows)
{
    __shared__ float As[32][132];
    __shared__ float Ws[32][132];
    int b = blockIdx.z;
    int r0 = blockIdx.x * 128, n0 = blockIdx.y * 128;
    int tid = threadIdx.x, tx = tid & 15, ty = tid >> 4;
    float acc[8][8] = {};
    for (int cc = 0; cc < VD; cc += 32) {
        #pragma unroll
        for (int e = 0; e < 16; ++e) {
            int flat = tid + e * 256;           // 4096 elems
            int r = flat >> 5, c = flat & 31;   // A: 128 rows x 32 k
            int gr = r0 + r;
            float v = 0.f;
            if (gr < rows) {
                int srow = GATHER ? idxws[b * LP + gr] : gr;
                v = src[((size_t)b * srcRows + srow) * VD + cc + c];
                if (PE) v += pe[gr * VD + cc + c];
            }
            As[c][r] = v;
            int kr = flat >> 7, nc = flat & 127; // W: 32 k x 128 n
            Ws[kr][nc] = W[(size_t)(cc + kr) * HID + n0 + nc];
        }
        __syncthreads();
        #pragma unroll
        for (int k = 0; k < 32; ++k) {
            float4 a0 = *(const float4*)&As[k][ty * 8];
            float4 a1 = *(const float4*)&As[k][ty * 8 + 4];
            float4 w0 = *(const float4*)&Ws[k][tx * 8];
            float4 w1 = *(const float4*)&Ws[k][tx * 8 + 4];
            float a[8] = {a0.x,a0.y,a0.z,a0.w,a1.x,a1.y,a1.z,a1.w};
            float w[8] = {w0.x,w0.y,w0.z,w0.w,w1.x,w1.y,w1.z,w1.w};
            #pragma unroll
            for (int i = 0; i < 8; ++i)
                #pragma unroll
                for (int j = 0; j < 8; ++j)
                    acc[i][j] = fmaf(a[i], w[j], acc[i][j]);
        }
        __syncthreads();
    }
    float bb[8];
    #pragma unroll
    for (int j = 0; j < 8; ++j) bb[j] = bias[n0 + tx * 8 + j];
    #pragma unroll
    for (int i = 0; i < 8; ++i) {
        int gr = r0 + ty * 8 + i;
        if (gr >= rows) continue;
        size_t o = ((size_t)b * rows + gr) * HID + n0 + tx * 8;
        unsigned int u[4];
        #pragma unroll
        for (int jj = 0; jj < 4; ++jj) {
            u[jj] = (unsigned int)f2bf(acc[i][2*jj] + bb[2*jj])
                  | ((unsigned int)f2bf(acc[i][2*jj+1] + bb[2*jj+1]) << 16);
        }
        uint4 pk = {u[0], u[1], u[2], u[3]};
        *(uint4*)&dst[o] = pk;
    }
}

// ---------------------------------------------------------------------------
// K4: attn_avg[b,v,q] = (Qp[b,v,:] . Kp[b,q,:]) / 64   (full 512-dim dot ==
// head-sum of per-head 64-dots; includes 1/SCALE and 1/NHEADS).
// 128x128 tile, 8x8/thread, k-chunk 32, both operands staged transposed.
// ---------------------------------------------------------------------------
__global__ __launch_bounds__(256) void attnavg_kernel(
    const unsigned short* __restrict__ Qp, const unsigned short* __restrict__ Kp,
    float* __restrict__ outA)
{
    __shared__ float Qs[32][132];
    __shared__ float Ks[32][132];
    int b = blockIdx.z;
    int q0 = blockIdx.x * 128, v0 = blockIdx.y * 128;
    int tid = threadIdx.x, tx = tid & 15, ty = tid >> 4;
    float acc[8][8] = {};
    for (int kk = 0; kk < HID; kk += 32) {
        #pragma unroll
        for (int e = 0; e < 16; ++e) {
            int flat = tid + e * 256;
            int r = flat >> 5, c = flat & 31;
            int gv = v0 + r;
            Qs[c][r] = (gv < LP) ? bf2f(Qp[((size_t)b * LP + gv) * HID + kk + c]) : 0.f;
            int gq = q0 + r;
            Ks[c][r] = (gq < LQ) ? bf2f(Kp[((size_t)b * LQ + gq) * HID + kk + c]) : 0.f;
        }
        __syncthreads();
        #pragma unroll
        for (int k = 0; k < 32; ++k) {
            float4 a0 = *(const float4*)&Qs[k][ty * 8];
            float4 a1 = *(const float4*)&Qs[k][ty * 8 + 4];
            float4 w0 = *(const float4*)&Ks[k][tx * 8];
            float4 w1 = *(const float4*)&Ks[k][tx * 8 + 4];
            float a[8] = {a0.x,a0.y,a0.z,a0.w,a1.x,a1.y,a1.z,a1.w};
            float w[8] = {w0.x,w0.y,w0.z,w0.w,w1.x,w1.y,w1.z,w1.w};
            #pragma unroll
            for (int i = 0; i < 8; ++i)
                #pragma unroll
                for (int j = 0; j < 8; ++j)
                    acc[i][j] = fmaf(a[i], w[j], acc[i][j]);
        }
        __syncthreads();
    }
    const float sc = 1.0f / 64.0f;
    #pragma unroll
    for (int i = 0; i < 8; ++i) {
        int gv = v0 + ty * 8 + i;
        if (gv >= LP) continue;
        int gq = q0 + tx * 8;
        if (gq + 8 <= LQ) {
            float* p = outA + ((size_t)b * LP + gv) * LQ + gq;
            float4 o0 = {acc[i][0]*sc, acc[i][1]*sc, acc[i][2]*sc, acc[i][3]*sc};
            float4 o1 = {acc[i][4]*sc, acc[i][5]*sc, acc[i][6]*sc, acc[i][7]*sc};
            *(float4*)p = o0; *(float4*)(p + 4) = o1;
        }
    }
}

// ---------------------------------------------------------------------------
// K5: per-(b,h) 64x64 outer-product GEMM  out[d,k] = sum_rows A[r,d]*B[r,k]
// used for M = Kp^T V2p (split into `gridDim.x` row-groups to ws slabs) and
// N = Qp^T V1p (single group).
// ---------------------------------------------------------------------------
__global__ __launch_bounds__(256) void pairgemm_kernel(
    const unsigned short* __restrict__ A, const unsigned short* __restrict__ Bm,
    int rows, int nch, float* __restrict__ outP)
{
    __shared__ float Ac[64][68];
    __shared__ float Bc[64][68];
    int g = blockIdx.x, G = gridDim.x;
    int bh = blockIdx.y;
    int b = bh >> 3, h = bh & 7;
    int tid = threadIdx.x, tx = tid & 15, ty = tid >> 4;
    float acc[4][4] = {};
    for (int ch = g; ch < nch; ch += G) {
        int row0 = ch * 64;
        #pragma unroll
        for (int e = 0; e < 16; ++e) {
            int flat = tid + e * 256;
            int r = flat >> 6, c = flat & 63;
            int gr = row0 + r;
            float av = 0.f, bv = 0.f;
            if (gr < rows) {
                size_t o = ((size_t)b * rows + gr) * HID + h * HD + c;
                av = bf2f(A[o]); bv = bf2f(Bm[o]);
            }
            Ac[r][c] = av; Bc[r][c] = bv;
        }
        __syncthreads();
        #pragma unroll
        for (int q = 0; q < 64; ++q) {
            float4 a = *(const float4*)&Ac[q][ty * 4];
            float4 w = *(const float4*)&Bc[q][tx * 4];
            float av[4] = {a.x,a.y,a.z,a.w}, wv[4] = {w.x,w.y,w.z,w.w};
            #pragma unroll
            for (int i = 0; i < 4; ++i)
                #pragma unroll
                for (int j = 0; j < 4; ++j)
                    acc[i][j] = fmaf(av[i], wv[j], acc[i][j]);
        }
        __syncthreads();
    }
    float* op = outP + ((size_t)g * 256 + bh) * 4096;
    #pragma unroll
    for (int i = 0; i < 4; ++i) {
        float4 o = {acc[i][0], acc[i][1], acc[i][2], acc[i][3]};
        *(float4*)&op[(ty * 4 + i) * 64 + tx * 4] = o;
    }
}

// ---------------------------------------------------------------------------
// K6: x[b, h*64+k] = BN( (1/8) * sum_d M[d,k]*N[d,k] )   (M summed over 5 slabs)
// ---------------------------------------------------------------------------
__global__ __launch_bounds__(256) void xout_kernel(
    const float* __restrict__ Mp, const float* __restrict__ Np,
    const float* __restrict__ gamma, const float* __restrict__ beta,
    const float* __restrict__ mean, const float* __restrict__ var,
    float* __restrict__ outX)
{
    int bh = blockIdx.x;
    int b = bh >> 3, h = bh & 7;
    int tid = threadIdx.x;
    int k = tid & 63, dg = tid >> 6;   // 4 d-groups of 16
    float s = 0.f;
    for (int d = dg * 16; d < dg * 16 + 16; ++d) {
        float m = 0.f;
        #pragma unroll
        for (int g = 0; g < 5; ++g)
            m += Mp[((size_t)g * 256 + bh) * 4096 + d * 64 + k];
        s += m * Np[(size_t)bh * 4096 + d * 64 + k];
    }
    __shared__ float red[4][64];
    red[dg][k] = s;
    __syncthreads();
    if (tid < 64) {
        float x = (red[0][tid] + red[1][tid] + red[2][tid] + red[3][tid]) * 0.125f;
        int c = h * HD + tid;
        float y = (x - mean[c]) * rsqrtf(var[c] + 1e-5f) * gamma[c] + beta[c];
        outX[(size_t)b * HID + c] = y;
    }
}

extern "C" void kernel_launch(void* const* d_in, const int* in_sizes, int n_in,
                              void* d_out, int out_size, void* d_ws, size_t ws_size,
                              hipStream_t stream) {
    const float* query = (const float*)d_in[0];
    const float* key   = (const float*)d_in[1];
    const float* att   = (const float*)d_in[2];
    const float* Wq  = (const float*)d_in[3];
    const float* bq  = (const float*)d_in[4];
    const float* Wk  = (const float*)d_in[5];
    const float* bk  = (const float*)d_in[6];
    const float* Wv1 = (const float*)d_in[7];
    const float* bv1 = (const float*)d_in[8];
    const float* Wv2 = (const float*)d_in[9];
    const float* bv2 = (const float*)d_in[10];
    const float* gamma = (const float*)d_in[11];
    const float* beta  = (const float*)d_in[12];
    const float* mean  = (const float*)d_in[13];
    const float* var   = (const float*)d_in[14];

    float* out    = (float*)d_out;
    float* outX   = out;             // [32,512]       16384
    float* outIdx = out + 16384;     // [32,200]       6400 (idx as float)
    float* outA   = out + 22784;     // [32,200,1200]  7,680,000

    char* ws = (char*)d_ws;
    size_t off = 0;
    auto carve = [&](size_t bytes) {
        void* p = ws + off; off += (bytes + 255) & ~(size_t)255; return p;
    };
    int*            idxws = (int*)carve((size_t)NB * LP * 4);
    float*          pe    = (float*)carve((size_t)LQ * VD * 4);
    unsigned short* Qp    = (unsigned short*)carve((size_t)NB * LP * HID * 2);
    unsigned short* Kp    = (unsigned short*)carve((size_t)NB * LQ * HID * 2);
    unsigned short* V1p   = (unsigned short*)carve((size_t)NB * LP * HID * 2);
    unsigned short* V2p   = (unsigned short*)carve((size_t)NB * LQ * HID * 2);
    float*          Mp    = (float*)carve((size_t)5 * 256 * 4096 * 4);
    float*          Np    = (float*)carve((size_t)256 * 4096 * 4);
    (void)ws_size; (void)in_sizes; (void)n_in; (void)out_size;

    topk_kernel<<<dim3(NB), dim3(256), 0, stream>>>(att, idxws, outIdx);
    pe_fill<<<dim3((LQ * VD + 255) / 256), dim3(256), 0, stream>>>(pe);

    proj_kernel<1,1><<<dim3(2, 4, NB), dim3(256), 0, stream>>>(
        query, LV, idxws, pe, Wq, bq, Qp, LP);
    proj_kernel<0,1><<<dim3(10, 4, NB), dim3(256), 0, stream>>>(
        key, LQ, nullptr, pe, Wk, bk, Kp, LQ);
    proj_kernel<1,0><<<dim3(2, 4, NB), dim3(256), 0, stream>>>(
        query, LV, idxws, pe, Wv1, bv1, V1p, LP);
    proj_kernel<0,0><<<dim3(10, 4, NB), dim3(256), 0, stream>>>(
        key, LQ, nullptr, pe, Wv2, bv2, V2p, LQ);

    attnavg_kernel<<<dim3(10, 2, NB), dim3(256), 0, stream>>>(Qp, Kp, outA);

    pairgemm_kernel<<<dim3(5, 256), dim3(256), 0, stream>>>(Kp, V2p, LQ, 19, Mp);
    pairgemm_kernel<<<dim3(1, 256), dim3(256), 0, stream>>>(Qp, V1p, LP, 4, Np);
    xout_kernel<<<dim3(256), dim3(256), 0, stream>>>(Mp, Np, gamma, beta, mean, var, outX);
}

// Round 2
// 549.056 us; speedup vs baseline: 1.9338x; 1.9338x over previous
//
#include <hip/hip_runtime.h>
#include <hip/hip_bf16.h>

#define NB 32
#define LV 1000
#define LQ 1200
#define VD 128
#define HID 512
#define NH 8
#define HD 64
#define LP 200   // len_pro = 0.2 * 1000

typedef __attribute__((ext_vector_type(8))) short s8v;   // 8 x bf16 (4 VGPR)
typedef __attribute__((ext_vector_type(4))) float f4v;   // 4 x f32 acc

union FragU { s8v v; unsigned short u[8]; };

__device__ __forceinline__ unsigned short f2bf(float f) {
    __hip_bfloat16 h = __float2bfloat16(f);
    return *reinterpret_cast<unsigned short*>(&h);
}

// ---------------------------------------------------------------------------
// K1: scores = max over 4 rows of att; stable top-200 via bitonic sort.
// ---------------------------------------------------------------------------
__global__ __launch_bounds__(256) void topk_kernel(const float* __restrict__ att,
                                                   int* __restrict__ idx_ws,
                                                   float* __restrict__ out_idx) {
    __shared__ float s[1024];
    __shared__ int   si[1024];
    int b = blockIdx.x, tid = threadIdx.x;
    for (int i = tid; i < 1024; i += 256) {
        float v = -INFINITY;
        if (i < LV) {
            const float* p = att + (size_t)b * 4 * LV + i;
            v = fmaxf(fmaxf(p[0], p[LV]), fmaxf(p[2 * LV], p[3 * LV]));
        }
        s[i] = v; si[i] = i;
    }
    __syncthreads();
    for (int k = 2; k <= 1024; k <<= 1) {
        for (int j = k >> 1; j > 0; j >>= 1) {
            for (int i = tid; i < 1024; i += 256) {
                int l = i ^ j;
                if (l > i) {
                    float a = s[i], c = s[l];
                    int ia = si[i], ic = si[l];
                    bool aFirst = (a > c) || (a == c && ia < ic);
                    bool desc = ((i & k) == 0);
                    if (desc != aFirst) { s[i] = c; s[l] = a; si[i] = ic; si[l] = ia; }
                }
            }
            __syncthreads();
        }
    }
    for (int i = tid; i < LP; i += 256) {
        int v = si[i];
        idx_ws[b * LP + i]  = v;
        out_idx[b * LP + i] = (float)v;
    }
}

// ---------------------------------------------------------------------------
// K2: sinusoidal PE table pe[1200][128] (rows 0..199 reused for gathered query)
// ---------------------------------------------------------------------------
__global__ __launch_bounds__(256) void pe_fill(float* __restrict__ pe) {
    int t = blockIdx.x * 256 + threadIdx.x;
    if (t >= LQ * VD) return;
    int r = t >> 7, c = t & 127;
    int i = c >> 1;
    float div = expf((float)(2 * i) * -0.07195578415606394f); // -ln(10000)/128
    float ang = (float)r * div;
    pe[t] = (c & 1) ? cosf(ang) : sinf(ang);
}

// ---------------------------------------------------------------------------
// K3: weight transpose+cast  Wt[n][k] = bf16(W[k][n])  (4 matrices, 64x64 tiles)
// ---------------------------------------------------------------------------
__global__ __launch_bounds__(256) void wtrans_kernel(
    const float* __restrict__ w0, const float* __restrict__ w1,
    const float* __restrict__ w2, const float* __restrict__ w3,
    unsigned short* __restrict__ t0, unsigned short* __restrict__ t1,
    unsigned short* __restrict__ t2, unsigned short* __restrict__ t3)
{
    __shared__ unsigned short Ts[64][72];
    const float* W; unsigned short* T;
    switch (blockIdx.z) {
        case 0:  W = w0; T = t0; break;
        case 1:  W = w1; T = t1; break;
        case 2:  W = w2; T = t2; break;
        default: W = w3; T = t3; break;
    }
    int k0 = blockIdx.x * 64, n0 = blockIdx.y * 64;
    int tid = threadIdx.x;
    #pragma unroll
    for (int e = 0; e < 2; ++e) {
        int flat = tid + e * 256;
        int kk = flat >> 3, n8 = (flat & 7) * 8;
        const float* p = W + (size_t)(k0 + kk) * HID + n0 + n8;
        float4 f0 = *(const float4*)p, f1 = *(const float4*)(p + 4);
        Ts[n8 + 0][kk] = f2bf(f0.x); Ts[n8 + 1][kk] = f2bf(f0.y);
        Ts[n8 + 2][kk] = f2bf(f0.z); Ts[n8 + 3][kk] = f2bf(f0.w);
        Ts[n8 + 4][kk] = f2bf(f1.x); Ts[n8 + 5][kk] = f2bf(f1.y);
        Ts[n8 + 6][kk] = f2bf(f1.z); Ts[n8 + 7][kk] = f2bf(f1.w);
    }
    __syncthreads();
    #pragma unroll
    for (int e = 0; e < 2; ++e) {
        int flat = tid + e * 256;
        int nn = flat >> 3, k8 = (flat & 7) * 8;
        uint4 pk;
        pk.x = (unsigned)Ts[nn][k8 + 0] | ((unsigned)Ts[nn][k8 + 1] << 16);
        pk.y = (unsigned)Ts[nn][k8 + 2] | ((unsigned)Ts[nn][k8 + 3] << 16);
        pk.z = (unsigned)Ts[nn][k8 + 4] | ((unsigned)Ts[nn][k8 + 5] << 16);
        pk.w = (unsigned)Ts[nn][k8 + 6] | ((unsigned)Ts[nn][k8 + 7] << 16);
        *(uint4*)&T[(size_t)(n0 + nn) * VD + k0 + k8] = pk;
    }
}

// ---------------------------------------------------------------------------
// K4: projection MFMA GEMM  dst[b,r,n] = bf16((src[row](+pe)) @ W + bias)
// fp32 src converted to bf16 fragments in-register; B-frags are 16B loads of
// pre-transposed bf16 Wt. 4 waves/block, each wave owns a 64x64 output tile.
// ---------------------------------------------------------------------------
template<int GATHER, int PE>
__global__ __launch_bounds__(256) void proj_kernel(
    const float* __restrict__ src, int srcRows,
    const int* __restrict__ idxws, const float* __restrict__ pe,
    const unsigned short* __restrict__ Wt, const float* __restrict__ bias,
    unsigned short* __restrict__ dst, int rows)
{
    int b = blockIdx.z;
    int lane = threadIdx.x & 63, w = threadIdx.x >> 6;
    int rbase = blockIdx.x * 128 + (w >> 1) * 64;
    int nbase = blockIdx.y * 128 + (w & 1) * 64;
    int lc = lane & 15, lg = lane >> 4;

    int srow[4], prow[4];
    #pragma unroll
    for (int i = 0; i < 4; ++i) {
        int rc = min(rbase + i * 16 + lc, rows - 1);
        prow[i] = rc;
        srow[i] = GATHER ? idxws[b * LP + rc] : rc;
    }

    f4v acc[4][4] = {};
    for (int kk = 0; kk < VD; kk += 32) {
        s8v af[4], bf[4];
        #pragma unroll
        for (int i = 0; i < 4; ++i) {
            const float* p = src + ((size_t)b * srcRows + srow[i]) * VD + kk + lg * 8;
            float4 f0 = *(const float4*)p, f1 = *(const float4*)(p + 4);
            float fv[8] = {f0.x, f0.y, f0.z, f0.w, f1.x, f1.y, f1.z, f1.w};
            if (PE) {
                const float* q = pe + (size_t)prow[i] * VD + kk + lg * 8;
                float4 p0 = *(const float4*)q, p1 = *(const float4*)(q + 4);
                float pv[8] = {p0.x, p0.y, p0.z, p0.w, p1.x, p1.y, p1.z, p1.w};
                #pragma unroll
                for (int e = 0; e < 8; ++e) fv[e] += pv[e];
            }
            FragU fu;
            #pragma unroll
            for (int e = 0; e < 8; ++e) fu.u[e] = f2bf(fv[e]);
            af[i] = fu.v;
        }
        #pragma unroll
        for (int j = 0; j < 4; ++j)
            bf[j] = *(const s8v*)&Wt[(size_t)(nbase + j * 16 + lc) * VD + kk + lg * 8];
        #pragma unroll
        for (int i = 0; i < 4; ++i)
            #pragma unroll
            for (int j = 0; j < 4; ++j)
                acc[i][j] = __builtin_amdgcn_mfma_f32_16x16x32_bf16(af[i], bf[j], acc[i][j], 0, 0, 0);
    }

    float bb[4];
    #pragma unroll
    for (int j = 0; j < 4; ++j) bb[j] = bias[nbase + j * 16 + lc];
    #pragma unroll
    for (int i = 0; i < 4; ++i) {
        #pragma unroll
        for (int reg = 0; reg < 4; ++reg) {
            int r = rbase + i * 16 + lg * 4 + reg;
            if (r >= rows) continue;
            #pragma unroll
            for (int j = 0; j < 4; ++j)
                dst[((size_t)b * rows + r) * HID + nbase + j * 16 + lc] =
                    f2bf(acc[i][j][reg] + bb[j]);
        }
    }
}

// ---------------------------------------------------------------------------
// K5: attn_avg[b,v,q] = (Qp[b,v,:].Kp[b,q,:]) / 64 — bf16 MFMA, no LDS.
// ---------------------------------------------------------------------------
__global__ __launch_bounds__(256) void attnavg_kernel(
    const unsigned short* __restrict__ Qp, const unsigned short* __restrict__ Kp,
    float* __restrict__ outA)
{
    int b = blockIdx.z;
    int lane = threadIdx.x & 63, w = threadIdx.x >> 6;
    int vbase = blockIdx.y * 128 + (w >> 1) * 64;
    int qbase = blockIdx.x * 128 + (w & 1) * 64;
    int lc = lane & 15, lg = lane >> 4;

    int vr[4], qr[4];
    #pragma unroll
    for (int i = 0; i < 4; ++i) vr[i] = min(vbase + i * 16 + lc, LP - 1);
    #pragma unroll
    for (int j = 0; j < 4; ++j) qr[j] = min(qbase + j * 16 + lc, LQ - 1);

    f4v acc[4][4] = {};
    for (int kk = 0; kk < HID; kk += 32) {
        s8v af[4], bf[4];
        #pragma unroll
        for (int i = 0; i < 4; ++i)
            af[i] = *(const s8v*)&Qp[((size_t)b * LP + vr[i]) * HID + kk + lg * 8];
        #pragma unroll
        for (int j = 0; j < 4; ++j)
            bf[j] = *(const s8v*)&Kp[((size_t)b * LQ + qr[j]) * HID + kk + lg * 8];
        #pragma unroll
        for (int i = 0; i < 4; ++i)
            #pragma unroll
            for (int j = 0; j < 4; ++j)
                acc[i][j] = __builtin_amdgcn_mfma_f32_16x16x32_bf16(af[i], bf[j], acc[i][j], 0, 0, 0);
    }
    #pragma unroll
    for (int i = 0; i < 4; ++i) {
        #pragma unroll
        for (int reg = 0; reg < 4; ++reg) {
            int v = vbase + i * 16 + lg * 4 + reg;
            if (v >= LP) continue;
            #pragma unroll
            for (int j = 0; j < 4; ++j) {
                int q = qbase + j * 16 + lc;
                if (q < LQ)
                    outA[((size_t)b * LP + v) * LQ + q] = acc[i][j][reg] * 0.015625f;
            }
        }
    }
}

// ---------------------------------------------------------------------------
// K6: Mp[bh][d][k] = sum_r Kp_h[r][d] * V2p_h[r][k]  (1 wave per (b,h))
// ---------------------------------------------------------------------------
__global__ __launch_bounds__(64) void pairM_kernel(
    const unsigned short* __restrict__ Kp, const unsigned short* __restrict__ V2p,
    float* __restrict__ Mp)
{
    int bh = blockIdx.x, b = bh >> 3, h = bh & 7;
    int lane = threadIdx.x, lc = lane & 15, lg = lane >> 4;
    f4v acc[4][4] = {};
    for (int it = 0; it < 38; ++it) {
        int r0 = it * 32 + lg * 8;
        s8v af[4], bf[4];
        #pragma unroll
        for (int i = 0; i < 4; ++i) {
            FragU fa, fb;
            int colA = h * HD + i * 16 + lc;
            #pragma unroll
            for (int e = 0; e < 8; ++e) {
                int r = r0 + e;
                size_t o = ((size_t)b * LQ + r) * HID;
                fa.u[e] = (r < LQ) ? Kp[o + colA]  : (unsigned short)0;
                fb.u[e] = (r < LQ) ? V2p[o + colA] : (unsigned short)0;
            }
            af[i] = fa.v; bf[i] = fb.v;
        }
        #pragma unroll
        for (int i = 0; i < 4; ++i)
            #pragma unroll
            for (int j = 0; j < 4; ++j)
                acc[i][j] = __builtin_amdgcn_mfma_f32_16x16x32_bf16(af[i], bf[j], acc[i][j], 0, 0, 0);
    }
    #pragma unroll
    for (int i = 0; i < 4; ++i)
        #pragma unroll
        for (int reg = 0; reg < 4; ++reg) {
            int d = i * 16 + lg * 4 + reg;
            #pragma unroll
            for (int j = 0; j < 4; ++j)
                Mp[(size_t)bh * 4096 + d * 64 + j * 16 + lc] = acc[i][j][reg];
        }
}

// ---------------------------------------------------------------------------
// K7: Np = Qp_h^T V1p_h (in-register), then x = BN((1/8) sum_d Mp.Np) fused.
// ---------------------------------------------------------------------------
__global__ __launch_bounds__(64) void pairNx_kernel(
    const unsigned short* __restrict__ Qp, const unsigned short* __restrict__ V1p,
    const float* __restrict__ Mp,
    const float* __restrict__ gamma, const float* __restrict__ beta,
    const float* __restrict__ mean, const float* __restrict__ var,
    float* __restrict__ outX)
{
    int bh = blockIdx.x, b = bh >> 3, h = bh & 7;
    int lane = threadIdx.x, lc = lane & 15, lg = lane >> 4;
    f4v acc[4][4] = {};
    for (int it = 0; it < 7; ++it) {
        int r0 = it * 32 + lg * 8;
        s8v af[4], bf[4];
        #pragma unroll
        for (int i = 0; i < 4; ++i) {
            FragU fa, fb;
            int colA = h * HD + i * 16 + lc;
            #pragma unroll
            for (int e = 0; e < 8; ++e) {
                int r = r0 + e;
                size_t o = ((size_t)b * LP + r) * HID;
                fa.u[e] = (r < LP) ? Qp[o + colA]  : (unsigned short)0;
                fb.u[e] = (r < LP) ? V1p[o + colA] : (unsigned short)0;
            }
            af[i] = fa.v; bf[i] = fb.v;
        }
        #pragma unroll
        for (int i = 0; i < 4; ++i)
            #pragma unroll
            for (int j = 0; j < 4; ++j)
                acc[i][j] = __builtin_amdgcn_mfma_f32_16x16x32_bf16(af[i], bf[j], acc[i][j], 0, 0, 0);
    }
    #pragma unroll
    for (int j = 0; j < 4; ++j) {
        float s = 0.f;
        #pragma unroll
        for (int i = 0; i < 4; ++i)
            #pragma unroll
            for (int reg = 0; reg < 4; ++reg) {
                int d = i * 16 + lg * 4 + reg;
                s += acc[i][j][reg] * Mp[(size_t)bh * 4096 + d * 64 + j * 16 + lc];
            }
        s += __shfl_xor(s, 16, 64);
        s += __shfl_xor(s, 32, 64);
        if (lg == 0) {
            int c = h * HD + j * 16 + lc;
            float x = s * 0.125f;
            outX[(size_t)b * HID + c] =
                (x - mean[c]) * rsqrtf(var[c] + 1e-5f) * gamma[c] + beta[c];
        }
    }
}

extern "C" void kernel_launch(void* const* d_in, const int* in_sizes, int n_in,
                              void* d_out, int out_size, void* d_ws, size_t ws_size,
                              hipStream_t stream) {
    const float* query = (const float*)d_in[0];
    const float* key   = (const float*)d_in[1];
    const float* att   = (const float*)d_in[2];
    const float* Wq  = (const float*)d_in[3];
    const float* bq  = (const float*)d_in[4];
    const float* Wk  = (const float*)d_in[5];
    const float* bk  = (const float*)d_in[6];
    const float* Wv1 = (const float*)d_in[7];
    const float* bv1 = (const float*)d_in[8];
    const float* Wv2 = (const float*)d_in[9];
    const float* bv2 = (const float*)d_in[10];
    const float* gamma = (const float*)d_in[11];
    const float* beta  = (const float*)d_in[12];
    const float* mean  = (const float*)d_in[13];
    const float* var   = (const float*)d_in[14];

    float* out    = (float*)d_out;
    float* outX   = out;             // [32,512]
    float* outIdx = out + 16384;     // [32,200] idx as float
    float* outA   = out + 22784;     // [32,200,1200]

    char* ws = (char*)d_ws;
    size_t off = 0;
    auto carve = [&](size_t bytes) {
        void* p = ws + off; off += (bytes + 255) & ~(size_t)255; return p;
    };
    int*            idxws = (int*)carve((size_t)NB * LP * 4);
    float*          pe    = (float*)carve((size_t)LQ * VD * 4);
    unsigned short* Wqt   = (unsigned short*)carve((size_t)HID * VD * 2);
    unsigned short* Wkt   = (unsigned short*)carve((size_t)HID * VD * 2);
    unsigned short* Wv1t  = (unsigned short*)carve((size_t)HID * VD * 2);
    unsigned short* Wv2t  = (unsigned short*)carve((size_t)HID * VD * 2);
    unsigned short* Qp    = (unsigned short*)carve((size_t)NB * LP * HID * 2);
    unsigned short* Kp    = (unsigned short*)carve((size_t)NB * LQ * HID * 2);
    unsigned short* V1p   = (unsigned short*)carve((size_t)NB * LP * HID * 2);
    unsigned short* V2p   = (unsigned short*)carve((size_t)NB * LQ * HID * 2);
    float*          Mp    = (float*)carve((size_t)256 * 4096 * 4);
    (void)ws_size; (void)in_sizes; (void)n_in; (void)out_size;

    topk_kernel<<<dim3(NB), dim3(256), 0, stream>>>(att, idxws, outIdx);
    pe_fill<<<dim3((LQ * VD + 255) / 256), dim3(256), 0, stream>>>(pe);
    wtrans_kernel<<<dim3(2, 8, 4), dim3(256), 0, stream>>>(
        Wq, Wk, Wv1, Wv2, Wqt, Wkt, Wv1t, Wv2t);

    proj_kernel<1, 1><<<dim3(2, 4, NB), dim3(256), 0, stream>>>(
        query, LV, idxws, pe, Wqt, bq, Qp, LP);
    proj_kernel<0, 1><<<dim3(10, 4, NB), dim3(256), 0, stream>>>(
        key, LQ, nullptr, pe, Wkt, bk, Kp, LQ);
    proj_kernel<1, 0><<<dim3(2, 4, NB), dim3(256), 0, stream>>>(
        query, LV, idxws, pe, Wv1t, bv1, V1p, LP);
    proj_kernel<0, 0><<<dim3(10, 4, NB), dim3(256), 0, stream>>>(
        key, LQ, nullptr, pe, Wv2t, bv2, V2p, LQ);

    attnavg_kernel<<<dim3(10, 2, NB), dim3(256), 0, stream>>>(Qp, Kp, outA);

    pairM_kernel<<<dim3(256), dim3(64), 0, stream>>>(Kp, V2p, Mp);
    pairNx_kernel<<<dim3(256), dim3(64), 0, stream>>>(
        Qp, V1p, Mp, gamma, beta, mean, var, outX);
}

// Round 3
// 378.524 us; speedup vs baseline: 2.8050x; 1.4505x over previous
//
#include <hip/hip_runtime.h>
#include <hip/hip_bf16.h>

#define NB 32
#define LV 1000
#define LQ 1200
#define VD 128
#define HID 512
#define NH 8
#define HD 64
#define LP 200    // len_pro = 0.2 * 1000
#define LQP 1216  // LQ padded to mult of 32
#define LPP 256   // LP padded (grid coverage of 2x128 row-tiles)
#define GM 4      // K-split slabs for pairM
#define GN 2      // K-split slabs for pairN

typedef __attribute__((ext_vector_type(8))) short s8v;   // 8 x bf16 (4 VGPR)
typedef __attribute__((ext_vector_type(4))) float f4v;   // 4 x f32 acc

union FragU { s8v v; unsigned short u[8]; };

__device__ __forceinline__ unsigned short f2bf(float f) {
    __hip_bfloat16 h = __float2bfloat16(f);
    return *reinterpret_cast<unsigned short*>(&h);
}

// ---------------------------------------------------------------------------
// K1: scores = max over 4 rows of att; stable top-200 via bitonic sort.
// ---------------------------------------------------------------------------
__global__ __launch_bounds__(256) void topk_kernel(const float* __restrict__ att,
                                                   int* __restrict__ idx_ws,
                                                   float* __restrict__ out_idx) {
    __shared__ float s[1024];
    __shared__ int   si[1024];
    int b = blockIdx.x, tid = threadIdx.x;
    for (int i = tid; i < 1024; i += 256) {
        float v = -INFINITY;
        if (i < LV) {
            const float* p = att + (size_t)b * 4 * LV + i;
            v = fmaxf(fmaxf(p[0], p[LV]), fmaxf(p[2 * LV], p[3 * LV]));
        }
        s[i] = v; si[i] = i;
    }
    __syncthreads();
    for (int k = 2; k <= 1024; k <<= 1) {
        for (int j = k >> 1; j > 0; j >>= 1) {
            for (int i = tid; i < 1024; i += 256) {
                int l = i ^ j;
                if (l > i) {
                    float a = s[i], c = s[l];
                    int ia = si[i], ic = si[l];
                    bool aFirst = (a > c) || (a == c && ia < ic);
                    bool desc = ((i & k) == 0);
                    if (desc != aFirst) { s[i] = c; s[l] = a; si[i] = ic; si[l] = ia; }
                }
            }
            __syncthreads();
        }
    }
    for (int i = tid; i < LP; i += 256) {
        int v = si[i];
        idx_ws[b * LP + i]  = v;
        out_idx[b * LP + i] = (float)v;
    }
}

// ---------------------------------------------------------------------------
// K2: sinusoidal PE table pe[1200][128]
// ---------------------------------------------------------------------------
__global__ __launch_bounds__(256) void pe_fill(float* __restrict__ pe) {
    int t = blockIdx.x * 256 + threadIdx.x;
    if (t >= LQ * VD) return;
    int r = t >> 7, c = t & 127;
    int i = c >> 1;
    float div = expf((float)(2 * i) * -0.07195578415606394f); // -ln(10000)/128
    float ang = (float)r * div;
    pe[t] = (c & 1) ? cosf(ang) : sinf(ang);
}

// ---------------------------------------------------------------------------
// K3: weight transpose+cast  Wt[n][k] = bf16(W[k][n])
// ---------------------------------------------------------------------------
__global__ __launch_bounds__(256) void wtrans_kernel(
    const float* __restrict__ w0, const float* __restrict__ w1,
    const float* __restrict__ w2, const float* __restrict__ w3,
    unsigned short* __restrict__ t0, unsigned short* __restrict__ t1,
    unsigned short* __restrict__ t2, unsigned short* __restrict__ t3)
{
    __shared__ unsigned short Ts[64][72];
    const float* W; unsigned short* T;
    switch (blockIdx.z) {
        case 0:  W = w0; T = t0; break;
        case 1:  W = w1; T = t1; break;
        case 2:  W = w2; T = t2; break;
        default: W = w3; T = t3; break;
    }
    int k0 = blockIdx.x * 64, n0 = blockIdx.y * 64;
    int tid = threadIdx.x;
    #pragma unroll
    for (int e = 0; e < 2; ++e) {
        int flat = tid + e * 256;
        int kk = flat >> 3, n8 = (flat & 7) * 8;
        const float* p = W + (size_t)(k0 + kk) * HID + n0 + n8;
        float4 f0 = *(const float4*)p, f1 = *(const float4*)(p + 4);
        Ts[n8 + 0][kk] = f2bf(f0.x); Ts[n8 + 1][kk] = f2bf(f0.y);
        Ts[n8 + 2][kk] = f2bf(f0.z); Ts[n8 + 3][kk] = f2bf(f0.w);
        Ts[n8 + 4][kk] = f2bf(f1.x); Ts[n8 + 5][kk] = f2bf(f1.y);
        Ts[n8 + 6][kk] = f2bf(f1.z); Ts[n8 + 7][kk] = f2bf(f1.w);
    }
    __syncthreads();
    #pragma unroll
    for (int e = 0; e < 2; ++e) {
        int flat = tid + e * 256;
        int nn = flat >> 3, k8 = (flat & 7) * 8;
        uint4 pk;
        pk.x = (unsigned)Ts[nn][k8 + 0] | ((unsigned)Ts[nn][k8 + 1] << 16);
        pk.y = (unsigned)Ts[nn][k8 + 2] | ((unsigned)Ts[nn][k8 + 3] << 16);
        pk.z = (unsigned)Ts[nn][k8 + 4] | ((unsigned)Ts[nn][k8 + 5] << 16);
        pk.w = (unsigned)Ts[nn][k8 + 6] | ((unsigned)Ts[nn][k8 + 7] << 16);
        *(uint4*)&T[(size_t)(n0 + nn) * VD + k0 + k8] = pk;
    }
}

// ---------------------------------------------------------------------------
// K4: projection MFMA GEMM. Optionally writes row-major (WRM) and/or
// per-column transposed (WRT) bf16 output. Transposed pad rows written as 0.
// ---------------------------------------------------------------------------
template<int GATHER, int PE, int WRM, int WRT>
__global__ __launch_bounds__(256) void proj_kernel(
    const float* __restrict__ src, int srcRows,
    const int* __restrict__ idxws, const float* __restrict__ pe,
    const unsigned short* __restrict__ Wt, const float* __restrict__ bias,
    unsigned short* __restrict__ dst, unsigned short* __restrict__ dstT,
    int rows, int Lpad)
{
    int b = blockIdx.z;
    int lane = threadIdx.x & 63, w = threadIdx.x >> 6;
    int rbase = blockIdx.x * 128 + (w >> 1) * 64;
    int nbase = blockIdx.y * 128 + (w & 1) * 64;
    int lc = lane & 15, lg = lane >> 4;

    int srow[4], prow[4];
    #pragma unroll
    for (int i = 0; i < 4; ++i) {
        int rc = min(rbase + i * 16 + lc, rows - 1);
        prow[i] = rc;
        srow[i] = GATHER ? idxws[b * LP + rc] : rc;
    }

    f4v acc[4][4] = {};
    for (int kk = 0; kk < VD; kk += 32) {
        s8v af[4], bf[4];
        #pragma unroll
        for (int i = 0; i < 4; ++i) {
            const float* p = src + ((size_t)b * srcRows + srow[i]) * VD + kk + lg * 8;
            float4 f0 = *(const float4*)p, f1 = *(const float4*)(p + 4);
            float fv[8] = {f0.x, f0.y, f0.z, f0.w, f1.x, f1.y, f1.z, f1.w};
            if (PE) {
                const float* q = pe + (size_t)prow[i] * VD + kk + lg * 8;
                float4 p0 = *(const float4*)q, p1 = *(const float4*)(q + 4);
                float pv[8] = {p0.x, p0.y, p0.z, p0.w, p1.x, p1.y, p1.z, p1.w};
                #pragma unroll
                for (int e = 0; e < 8; ++e) fv[e] += pv[e];
            }
            FragU fu;
            #pragma unroll
            for (int e = 0; e < 8; ++e) fu.u[e] = f2bf(fv[e]);
            af[i] = fu.v;
        }
        #pragma unroll
        for (int j = 0; j < 4; ++j)
            bf[j] = *(const s8v*)&Wt[(size_t)(nbase + j * 16 + lc) * VD + kk + lg * 8];
        #pragma unroll
        for (int i = 0; i < 4; ++i)
            #pragma unroll
            for (int j = 0; j < 4; ++j)
                acc[i][j] = __builtin_amdgcn_mfma_f32_16x16x32_bf16(af[i], bf[j], acc[i][j], 0, 0, 0);
    }

    float bb[4];
    #pragma unroll
    for (int j = 0; j < 4; ++j) bb[j] = bias[nbase + j * 16 + lc];

    if (WRM) {
        #pragma unroll
        for (int i = 0; i < 4; ++i) {
            #pragma unroll
            for (int reg = 0; reg < 4; ++reg) {
                int r = rbase + i * 16 + lg * 4 + reg;
                if (r >= rows) continue;
                #pragma unroll
                for (int j = 0; j < 4; ++j)
                    dst[((size_t)b * rows + r) * HID + nbase + j * 16 + lc] =
                        f2bf(acc[i][j][reg] + bb[j]);
            }
        }
    }
    if (WRT) {
        #pragma unroll
        for (int i = 0; i < 4; ++i) {
            int rb = rbase + i * 16 + lg * 4;
            if (rb >= Lpad) continue;
            #pragma unroll
            for (int j = 0; j < 4; ++j) {
                int n = nbase + j * 16 + lc;
                unsigned short hv[4];
                #pragma unroll
                for (int reg = 0; reg < 4; ++reg) {
                    int r = rb + reg;
                    hv[reg] = (r < rows) ? f2bf(acc[i][j][reg] + bb[j]) : (unsigned short)0;
                }
                uint2 pk;
                pk.x = (unsigned)hv[0] | ((unsigned)hv[1] << 16);
                pk.y = (unsigned)hv[2] | ((unsigned)hv[3] << 16);
                *(uint2*)&dstT[((size_t)b * HID + n) * Lpad + rb] = pk;
            }
        }
    }
}

// ---------------------------------------------------------------------------
// K5: attn_avg[b,v,q] = (Qp[b,v,:].Kp[b,q,:]) / 64 — bf16 MFMA, no LDS.
// ---------------------------------------------------------------------------
__global__ __launch_bounds__(256) void attnavg_kernel(
    const unsigned short* __restrict__ Qp, const unsigned short* __restrict__ Kp,
    float* __restrict__ outA)
{
    int b = blockIdx.z;
    int lane = threadIdx.x & 63, w = threadIdx.x >> 6;
    int vbase = blockIdx.y * 128 + (w >> 1) * 64;
    int qbase = blockIdx.x * 128 + (w & 1) * 64;
    int lc = lane & 15, lg = lane >> 4;

    int vr[4], qr[4];
    #pragma unroll
    for (int i = 0; i < 4; ++i) vr[i] = min(vbase + i * 16 + lc, LP - 1);
    #pragma unroll
    for (int j = 0; j < 4; ++j) qr[j] = min(qbase + j * 16 + lc, LQ - 1);

    f4v acc[4][4] = {};
    for (int kk = 0; kk < HID; kk += 32) {
        s8v af[4], bf[4];
        #pragma unroll
        for (int i = 0; i < 4; ++i)
            af[i] = *(const s8v*)&Qp[((size_t)b * LP + vr[i]) * HID + kk + lg * 8];
        #pragma unroll
        for (int j = 0; j < 4; ++j)
            bf[j] = *(const s8v*)&Kp[((size_t)b * LQ + qr[j]) * HID + kk + lg * 8];
        #pragma unroll
        for (int i = 0; i < 4; ++i)
            #pragma unroll
            for (int j = 0; j < 4; ++j)
                acc[i][j] = __builtin_amdgcn_mfma_f32_16x16x32_bf16(af[i], bf[j], acc[i][j], 0, 0, 0);
    }
    #pragma unroll
    for (int i = 0; i < 4; ++i) {
        #pragma unroll
        for (int reg = 0; reg < 4; ++reg) {
            int v = vbase + i * 16 + lg * 4 + reg;
            if (v >= LP) continue;
            #pragma unroll
            for (int j = 0; j < 4; ++j) {
                int q = qbase + j * 16 + lc;
                if (q < LQ)
                    outA[((size_t)b * LP + v) * LQ + q] = acc[i][j][reg] * 0.015625f;
            }
        }
    }
}

// ---------------------------------------------------------------------------
// K6: pair GEMM over transposed operands: out[d][k] = sum_r A[r,d]*B[r,k].
// A,B stored per-column: At[b][c][r] (r contiguous). K-split into slabs.
// ---------------------------------------------------------------------------
template<int LPAD, int NCH, int G>
__global__ __launch_bounds__(64) void pair_kernel(
    const unsigned short* __restrict__ At, const unsigned short* __restrict__ Bt,
    float* __restrict__ outP)
{
    int g = blockIdx.x;
    int bh = blockIdx.y, b = bh >> 3, h = bh & 7;
    int lane = threadIdx.x, lc = lane & 15, lg = lane >> 4;
    const unsigned short* Ah = At + ((size_t)b * HID + h * HD) * LPAD;
    const unsigned short* Bh = Bt + ((size_t)b * HID + h * HD) * LPAD;
    f4v acc[4][4] = {};
    for (int c = g; c < NCH; c += G) {
        int r0 = c * 32 + lg * 8;
        s8v af[4], bf[4];
        #pragma unroll
        for (int i = 0; i < 4; ++i)
            af[i] = *(const s8v*)&Ah[(size_t)(i * 16 + lc) * LPAD + r0];
        #pragma unroll
        for (int j = 0; j < 4; ++j)
            bf[j] = *(const s8v*)&Bh[(size_t)(j * 16 + lc) * LPAD + r0];
        #pragma unroll
        for (int i = 0; i < 4; ++i)
            #pragma unroll
            for (int j = 0; j < 4; ++j)
                acc[i][j] = __builtin_amdgcn_mfma_f32_16x16x32_bf16(af[i], bf[j], acc[i][j], 0, 0, 0);
    }
    float* op = outP + ((size_t)g * 256 + bh) * 4096;
    #pragma unroll
    for (int i = 0; i < 4; ++i)
        #pragma unroll
        for (int reg = 0; reg < 4; ++reg) {
            int d = i * 16 + lg * 4 + reg;
            #pragma unroll
            for (int j = 0; j < 4; ++j)
                op[d * 64 + j * 16 + lc] = acc[i][j][reg];
        }
}

// ---------------------------------------------------------------------------
// K7: x[b,h*64+k] = BN((1/8) sum_d (sum_g Mp)(sum_g Np))
// ---------------------------------------------------------------------------
__global__ __launch_bounds__(256) void xout_kernel(
    const float* __restrict__ Mp, const float* __restrict__ Np,
    const float* __restrict__ gamma, const float* __restrict__ beta,
    const float* __restrict__ mean, const float* __restrict__ var,
    float* __restrict__ outX)
{
    int bh = blockIdx.x, b = bh >> 3, h = bh & 7;
    int tid = threadIdx.x;
    int k = tid & 63, dg = tid >> 6;
    float s = 0.f;
    for (int d = dg * 16; d < dg * 16 + 16; ++d) {
        int o = d * 64 + k;
        float m = 0.f, n = 0.f;
        #pragma unroll
        for (int g = 0; g < GM; ++g) m += Mp[((size_t)g * 256 + bh) * 4096 + o];
        #pragma unroll
        for (int g = 0; g < GN; ++g) n += Np[((size_t)g * 256 + bh) * 4096 + o];
        s += m * n;
    }
    __shared__ float red[4][64];
    red[dg][k] = s;
    __syncthreads();
    if (tid < 64) {
        float x = (red[0][tid] + red[1][tid] + red[2][tid] + red[3][tid]) * 0.125f;
        int c = h * HD + tid;
        outX[(size_t)b * HID + c] =
            (x - mean[c]) * rsqrtf(var[c] + 1e-5f) * gamma[c] + beta[c];
    }
}

extern "C" void kernel_launch(void* const* d_in, const int* in_sizes, int n_in,
                              void* d_out, int out_size, void* d_ws, size_t ws_size,
                              hipStream_t stream) {
    const float* query = (const float*)d_in[0];
    const float* key   = (const float*)d_in[1];
    const float* att   = (const float*)d_in[2];
    const float* Wq  = (const float*)d_in[3];
    const float* bq  = (const float*)d_in[4];
    const float* Wk  = (const float*)d_in[5];
    const float* bk  = (const float*)d_in[6];
    const float* Wv1 = (const float*)d_in[7];
    const float* bv1 = (const float*)d_in[8];
    const float* Wv2 = (const float*)d_in[9];
    const float* bv2 = (const float*)d_in[10];
    const float* gamma = (const float*)d_in[11];
    const float* beta  = (const float*)d_in[12];
    const float* mean  = (const float*)d_in[13];
    const float* var   = (const float*)d_in[14];

    float* out    = (float*)d_out;
    float* outX   = out;             // [32,512]
    float* outIdx = out + 16384;     // [32,200] idx as float
    float* outA   = out + 22784;     // [32,200,1200]

    char* ws = (char*)d_ws;
    size_t off = 0;
    auto carve = [&](size_t bytes) {
        void* p = ws + off; off += (bytes + 255) & ~(size_t)255; return p;
    };
    int*            idxws = (int*)carve((size_t)NB * LP * 4);
    unsigned short* Wqt   = (unsigned short*)carve((size_t)HID * VD * 2);
    unsigned short* Wkt   = (unsigned short*)carve((size_t)HID * VD * 2);
    unsigned short* Wv1t  = (unsigned short*)carve((size_t)HID * VD * 2);
    unsigned short* Wv2t  = (unsigned short*)carve((size_t)HID * VD * 2);
    unsigned short* Kp    = (unsigned short*)carve((size_t)NB * LQ * HID * 2);  // 39.3 MB
    unsigned short* Qt    = (unsigned short*)carve((size_t)NB * HID * LPP * 2);
    unsigned short* Kt    = (unsigned short*)carve((size_t)NB * HID * LQP * 2);
    unsigned short* V1t   = (unsigned short*)carve((size_t)NB * HID * LPP * 2);
    unsigned short* V2t   = (unsigned short*)carve((size_t)NB * HID * LQP * 2);
    float*          pe    = (float*)carve((size_t)LQ * VD * 4);
    unsigned short* Qp    = (unsigned short*)carve((size_t)NB * LP * HID * 2);
    // Mp/Np alias Kp (dead after attnavg): GM*4MB + GN*4MB = 25.2MB <= 39.3MB
    float* Mp = (float*)Kp;
    float* Np = (float*)((char*)Kp + (size_t)GM * 256 * 4096 * 4);
    (void)ws_size; (void)in_sizes; (void)n_in; (void)out_size;

    topk_kernel<<<dim3(NB), dim3(256), 0, stream>>>(att, idxws, outIdx);
    pe_fill<<<dim3((LQ * VD + 255) / 256), dim3(256), 0, stream>>>(pe);
    wtrans_kernel<<<dim3(2, 8, 4), dim3(256), 0, stream>>>(
        Wq, Wk, Wv1, Wv2, Wqt, Wkt, Wv1t, Wv2t);

    proj_kernel<1, 1, 1, 1><<<dim3(2, 4, NB), dim3(256), 0, stream>>>(
        query, LV, idxws, pe, Wqt, bq, Qp, Qt, LP, LPP);
    proj_kernel<0, 1, 1, 1><<<dim3(10, 4, NB), dim3(256), 0, stream>>>(
        key, LQ, nullptr, pe, Wkt, bk, Kp, Kt, LQ, LQP);
    proj_kernel<1, 0, 0, 1><<<dim3(2, 4, NB), dim3(256), 0, stream>>>(
        query, LV, idxws, pe, Wv1t, bv1, nullptr, V1t, LP, LPP);
    proj_kernel<0, 0, 0, 1><<<dim3(10, 4, NB), dim3(256), 0, stream>>>(
        key, LQ, nullptr, pe, Wv2t, bv2, nullptr, V2t, LQ, LQP);

    attnavg_kernel<<<dim3(10, 2, NB), dim3(256), 0, stream>>>(Qp, Kp, outA);

    // pairM: M = Kt^T-contract V2t, 38 chunks of 32 rows, GM slabs
    pair_kernel<LQP, 38, GM><<<dim3(GM, 256), dim3(64), 0, stream>>>(Kt, V2t, Mp);
    // pairN: N = Qt-contract V1t, 8 chunks, GN slabs
    pair_kernel<LPP, 8, GN><<<dim3(GN, 256), dim3(64), 0, stream>>>(Qt, V1t, Np);

    xout_kernel<<<dim3(256), dim3(256), 0, stream>>>(
        Mp, Np, gamma, beta, mean, var, outX);
}

// Round 4
// 338.225 us; speedup vs baseline: 3.1392x; 1.1191x over previous
//
#include <hip/hip_runtime.h>
#include <hip/hip_bf16.h>

#define NB 32
#define LV 1000
#define LQ 1200
#define VD 128
#define HID 512
#define NH 8
#define HD 64
#define LP 200    // len_pro = 0.2 * 1000
#define LQP 1216  // LQ padded to mult of 32
#define LPP 256   // LP padded
#define GM 4      // K-split slabs for pairM
#define GN 2      // K-split slabs for pairN

typedef __attribute__((ext_vector_type(8))) short s8v;   // 8 x bf16 (4 VGPR)
typedef __attribute__((ext_vector_type(4))) float f4v;   // 4 x f32 acc

union FragU { s8v v; unsigned short u[8]; };

__device__ __forceinline__ unsigned short f2bf(float f) {
    __hip_bfloat16 h = __float2bfloat16(f);
    return *reinterpret_cast<unsigned short*>(&h);
}

// ---------------------------------------------------------------------------
// K1: scores = max over 4 rows of att; stable top-200 via bitonic sort.
// ---------------------------------------------------------------------------
__global__ __launch_bounds__(256) void topk_kernel(const float* __restrict__ att,
                                                   int* __restrict__ idx_ws,
                                                   float* __restrict__ out_idx) {
    __shared__ float s[1024];
    __shared__ int   si[1024];
    int b = blockIdx.x, tid = threadIdx.x;
    for (int i = tid; i < 1024; i += 256) {
        float v = -INFINITY;
        if (i < LV) {
            const float* p = att + (size_t)b * 4 * LV + i;
            v = fmaxf(fmaxf(p[0], p[LV]), fmaxf(p[2 * LV], p[3 * LV]));
        }
        s[i] = v; si[i] = i;
    }
    __syncthreads();
    for (int k = 2; k <= 1024; k <<= 1) {
        for (int j = k >> 1; j > 0; j >>= 1) {
            for (int i = tid; i < 1024; i += 256) {
                int l = i ^ j;
                if (l > i) {
                    float a = s[i], c = s[l];
                    int ia = si[i], ic = si[l];
                    bool aFirst = (a > c) || (a == c && ia < ic);
                    bool desc = ((i & k) == 0);
                    if (desc != aFirst) { s[i] = c; s[l] = a; si[i] = ic; si[l] = ia; }
                }
            }
            __syncthreads();
        }
    }
    for (int i = tid; i < LP; i += 256) {
        int v = si[i];
        idx_ws[b * LP + i]  = v;
        out_idx[b * LP + i] = (float)v;
    }
}

// ---------------------------------------------------------------------------
// K2: prep = pe_fill (blocks 0..599) + weight transpose (blocks 600..663)
// ---------------------------------------------------------------------------
__global__ __launch_bounds__(256) void prep_kernel(
    float* __restrict__ pe,
    const float* __restrict__ w0, const float* __restrict__ w1,
    const float* __restrict__ w2, const float* __restrict__ w3,
    unsigned short* __restrict__ t0, unsigned short* __restrict__ t1,
    unsigned short* __restrict__ t2, unsigned short* __restrict__ t3)
{
    __shared__ unsigned short Ts[64][72];
    int bx = blockIdx.x, tid = threadIdx.x;
    if (bx < 600) {
        int t = bx * 256 + tid;
        if (t < LQ * VD) {
            int r = t >> 7, c = t & 127;
            int i = c >> 1;
            float div = expf((float)(2 * i) * -0.07195578415606394f);
            float ang = (float)r * div;
            pe[t] = (c & 1) ? cosf(ang) : sinf(ang);
        }
        return;
    }
    int idx = bx - 600;          // 0..63
    int mat = idx >> 4, rem = idx & 15;
    int k0 = (rem & 1) * 64, n0 = (rem >> 1) * 64;
    const float* W; unsigned short* T;
    switch (mat) {
        case 0:  W = w0; T = t0; break;
        case 1:  W = w1; T = t1; break;
        case 2:  W = w2; T = t2; break;
        default: W = w3; T = t3; break;
    }
    #pragma unroll
    for (int e = 0; e < 2; ++e) {
        int flat = tid + e * 256;
        int kk = flat >> 3, n8 = (flat & 7) * 8;
        const float* p = W + (size_t)(k0 + kk) * HID + n0 + n8;
        float4 f0 = *(const float4*)p, f1 = *(const float4*)(p + 4);
        Ts[n8 + 0][kk] = f2bf(f0.x); Ts[n8 + 1][kk] = f2bf(f0.y);
        Ts[n8 + 2][kk] = f2bf(f0.z); Ts[n8 + 3][kk] = f2bf(f0.w);
        Ts[n8 + 4][kk] = f2bf(f1.x); Ts[n8 + 5][kk] = f2bf(f1.y);
        Ts[n8 + 6][kk] = f2bf(f1.z); Ts[n8 + 7][kk] = f2bf(f1.w);
    }
    __syncthreads();
    #pragma unroll
    for (int e = 0; e < 2; ++e) {
        int flat = tid + e * 256;
        int nn = flat >> 3, k8 = (flat & 7) * 8;
        uint4 pk;
        pk.x = (unsigned)Ts[nn][k8 + 0] | ((unsigned)Ts[nn][k8 + 1] << 16);
        pk.y = (unsigned)Ts[nn][k8 + 2] | ((unsigned)Ts[nn][k8 + 3] << 16);
        pk.z = (unsigned)Ts[nn][k8 + 4] | ((unsigned)Ts[nn][k8 + 5] << 16);
        pk.w = (unsigned)Ts[nn][k8 + 6] | ((unsigned)Ts[nn][k8 + 7] << 16);
        *(uint4*)&T[(size_t)(n0 + nn) * VD + k0 + k8] = pk;
    }
}

// ---------------------------------------------------------------------------
// K3: all 4 projections in one launch. blockIdx.z = p*32+b, p: 0=K,1=V2,2=Q,3=V1.
// Epilogues LDS-repacked per wave (no barriers): row-major (K,Q) and
// transposed (all). Pad rows in transposed output written as 0.
// ---------------------------------------------------------------------------
__global__ __launch_bounds__(256) void proj_kernel(
    const float* __restrict__ query, const float* __restrict__ key,
    const int* __restrict__ idxws, const float* __restrict__ pe,
    const unsigned short* __restrict__ Wqt, const unsigned short* __restrict__ Wkt,
    const unsigned short* __restrict__ Wv1t, const unsigned short* __restrict__ Wv2t,
    const float* __restrict__ bq, const float* __restrict__ bk,
    const float* __restrict__ bv1, const float* __restrict__ bv2,
    unsigned short* __restrict__ Qp, unsigned short* __restrict__ Kp,
    unsigned short* __restrict__ Qt, unsigned short* __restrict__ Kt,
    unsigned short* __restrict__ V1t, unsigned short* __restrict__ V2t)
{
    __shared__ unsigned short Tls[4][64][72];
    int z = blockIdx.z;
    int p = z >> 5, b = z & 31;
    bool gath = (p >= 2);
    if (gath && blockIdx.x >= 2) return;

    const float* src = gath ? query : key;
    int srcRows = gath ? LV : LQ;
    int rows    = gath ? LP : LQ;
    int Lpad    = gath ? LPP : LQP;
    bool usePE  = (p == 0) || (p == 2);
    const unsigned short* Wt = (p == 0) ? Wkt : (p == 1) ? Wv2t : (p == 2) ? Wqt : Wv1t;
    const float* bias        = (p == 0) ? bk  : (p == 1) ? bv2  : (p == 2) ? bq  : bv1;
    unsigned short* dst  = (p == 0) ? Kp : (p == 2) ? Qp : nullptr;
    unsigned short* dstT = (p == 0) ? Kt : (p == 1) ? V2t : (p == 2) ? Qt : V1t;

    int lane = threadIdx.x & 63, w = threadIdx.x >> 6;
    int rbase = blockIdx.x * 128 + (w >> 1) * 64;
    int nbase = blockIdx.y * 128 + (w & 1) * 64;
    if (rbase >= Lpad) return;
    int lc = lane & 15, lg = lane >> 4;

    int srow[4], prow[4];
    #pragma unroll
    for (int i = 0; i < 4; ++i) {
        int rc = min(rbase + i * 16 + lc, rows - 1);
        prow[i] = rc;
        srow[i] = gath ? idxws[b * LP + rc] : rc;
    }

    f4v acc[4][4] = {};
    for (int kk = 0; kk < VD; kk += 32) {
        s8v af[4], bfr[4];
        #pragma unroll
        for (int i = 0; i < 4; ++i) {
            const float* pp = src + ((size_t)b * srcRows + srow[i]) * VD + kk + lg * 8;
            float4 f0 = *(const float4*)pp, f1 = *(const float4*)(pp + 4);
            float fv[8] = {f0.x, f0.y, f0.z, f0.w, f1.x, f1.y, f1.z, f1.w};
            if (usePE) {
                const float* q = pe + (size_t)prow[i] * VD + kk + lg * 8;
                float4 p0 = *(const float4*)q, p1 = *(const float4*)(q + 4);
                float pv[8] = {p0.x, p0.y, p0.z, p0.w, p1.x, p1.y, p1.z, p1.w};
                #pragma unroll
                for (int e = 0; e < 8; ++e) fv[e] += pv[e];
            }
            FragU fu;
            #pragma unroll
            for (int e = 0; e < 8; ++e) fu.u[e] = f2bf(fv[e]);
            af[i] = fu.v;
        }
        #pragma unroll
        for (int j = 0; j < 4; ++j)
            bfr[j] = *(const s8v*)&Wt[(size_t)(nbase + j * 16 + lc) * VD + kk + lg * 8];
        #pragma unroll
        for (int i = 0; i < 4; ++i)
            #pragma unroll
            for (int j = 0; j < 4; ++j)
                acc[i][j] = __builtin_amdgcn_mfma_f32_16x16x32_bf16(af[i], bfr[j], acc[i][j], 0, 0, 0);
    }

    float bb[4];
    #pragma unroll
    for (int j = 0; j < 4; ++j) bb[j] = bias[nbase + j * 16 + lc];

    unsigned short* Tw = &Tls[w][0][0];   // [64][72] per-wave, wave-synchronous

    if (dst) {
        // row-major repack: Tw[r][n]
        #pragma unroll
        for (int i = 0; i < 4; ++i)
            #pragma unroll
            for (int j = 0; j < 4; ++j)
                #pragma unroll
                for (int reg = 0; reg < 4; ++reg)
                    Tw[(i * 16 + lg * 4 + reg) * 72 + j * 16 + lc] =
                        f2bf(acc[i][j][reg] + bb[j]);
        #pragma unroll
        for (int e = 0; e < 8; ++e) {
            int c = lane + e * 64;
            int rr = c >> 3, cc = (c & 7) * 8;
            s8v vv = *(const s8v*)&Tw[rr * 72 + cc];
            int gr = rbase + rr;
            if (gr < rows)
                *(s8v*)&dst[((size_t)b * rows + gr) * HID + nbase + cc] = vv;
        }
    }
    // transposed repack: Tw[n][r], pad rows -> 0
    #pragma unroll
    for (int i = 0; i < 4; ++i)
        #pragma unroll
        for (int j = 0; j < 4; ++j)
            #pragma unroll
            for (int reg = 0; reg < 4; ++reg) {
                int r = rbase + i * 16 + lg * 4 + reg;
                Tw[(j * 16 + lc) * 72 + i * 16 + lg * 4 + reg] =
                    (r < rows) ? f2bf(acc[i][j][reg] + bb[j]) : (unsigned short)0;
            }
    #pragma unroll
    for (int e = 0; e < 8; ++e) {
        int c = lane + e * 64;
        int nn = c >> 3, cc = (c & 7) * 8;
        s8v vv = *(const s8v*)&Tw[nn * 72 + cc];
        *(s8v*)&dstT[((size_t)b * HID + nbase + nn) * Lpad + rbase + cc] = vv;
    }
}

// ---------------------------------------------------------------------------
// K4: attn_avg[b,v,q] = (Qp[b,v,:].Kp[b,q,:]) / 64 — MFMA + LDS-repacked stores
// ---------------------------------------------------------------------------
__global__ __launch_bounds__(256) void attnavg_kernel(
    const unsigned short* __restrict__ Qp, const unsigned short* __restrict__ Kp,
    float* __restrict__ outA)
{
    __shared__ float Tf[4][32][68];
    int b = blockIdx.z;
    int lane = threadIdx.x & 63, w = threadIdx.x >> 6;
    int vbase = blockIdx.y * 128 + (w >> 1) * 64;
    int qbase = blockIdx.x * 128 + (w & 1) * 64;
    if (qbase >= LQ || vbase >= LP) return;
    int lc = lane & 15, lg = lane >> 4;

    int vr[4], qr[4];
    #pragma unroll
    for (int i = 0; i < 4; ++i) vr[i] = min(vbase + i * 16 + lc, LP - 1);
    #pragma unroll
    for (int j = 0; j < 4; ++j) qr[j] = min(qbase + j * 16 + lc, LQ - 1);

    f4v acc[4][4] = {};
    for (int kk = 0; kk < HID; kk += 32) {
        s8v af[4], bfr[4];
        #pragma unroll
        for (int i = 0; i < 4; ++i)
            af[i] = *(const s8v*)&Qp[((size_t)b * LP + vr[i]) * HID + kk + lg * 8];
        #pragma unroll
        for (int j = 0; j < 4; ++j)
            bfr[j] = *(const s8v*)&Kp[((size_t)b * LQ + qr[j]) * HID + kk + lg * 8];
        #pragma unroll
        for (int i = 0; i < 4; ++i)
            #pragma unroll
            for (int j = 0; j < 4; ++j)
                acc[i][j] = __builtin_amdgcn_mfma_f32_16x16x32_bf16(af[i], bfr[j], acc[i][j], 0, 0, 0);
    }

    float* Tw = &Tf[w][0][0];   // [32][68] per wave
    #pragma unroll
    for (int round = 0; round < 2; ++round) {
        #pragma unroll
        for (int ii = 0; ii < 2; ++ii) {
            int i = round * 2 + ii;
            #pragma unroll
            for (int j = 0; j < 4; ++j)
                #pragma unroll
                for (int reg = 0; reg < 4; ++reg)
                    Tw[(ii * 16 + lg * 4 + reg) * 68 + j * 16 + lc] =
                        acc[i][j][reg] * 0.015625f;
        }
        #pragma unroll
        for (int e = 0; e < 8; ++e) {
            int c = lane + e * 64;
            int rr = c >> 4, cc = (c & 15) * 4;
            float4 vv = *(const float4*)&Tw[rr * 68 + cc];
            int gv = vbase + round * 32 + rr;
            int gq = qbase + cc;
            if (gv < LP && gq < LQ)
                *(float4*)&outA[((size_t)b * LP + gv) * LQ + gq] = vv;
        }
    }
}

// ---------------------------------------------------------------------------
// K5: merged pair GEMMs: M = Kt~V2t (GM slabs), N = Qt~V1t (GN slabs).
// out[d][k] = sum_r A[r,d]*B[r,k], operands stored per-column (r contiguous).
// ---------------------------------------------------------------------------
__global__ __launch_bounds__(64) void pair_kernel(
    const unsigned short* __restrict__ Kt, const unsigned short* __restrict__ V2t,
    const unsigned short* __restrict__ Qt, const unsigned short* __restrict__ V1t,
    float* __restrict__ Mp, float* __restrict__ Np)
{
    int g = blockIdx.x;
    const unsigned short *At, *Bt; float* outP;
    int LPAD, NCH, G, slab;
    if (g < GM) { At = Kt; Bt = V2t; outP = Mp; LPAD = LQP; NCH = 38; G = GM; slab = g; }
    else        { At = Qt; Bt = V1t; outP = Np; LPAD = LPP; NCH = 8;  G = GN; slab = g - GM; }
    int bh = blockIdx.y, b = bh >> 3, h = bh & 7;
    int lane = threadIdx.x, lc = lane & 15, lg = lane >> 4;
    const unsigned short* Ah = At + ((size_t)b * HID + h * HD) * LPAD;
    const unsigned short* Bh = Bt + ((size_t)b * HID + h * HD) * LPAD;
    f4v acc[4][4] = {};
    for (int c = slab; c < NCH; c += G) {
        int r0 = c * 32 + lg * 8;
        s8v af[4], bfr[4];
        #pragma unroll
        for (int i = 0; i < 4; ++i)
            af[i] = *(const s8v*)&Ah[(size_t)(i * 16 + lc) * LPAD + r0];
        #pragma unroll
        for (int j = 0; j < 4; ++j)
            bfr[j] = *(const s8v*)&Bh[(size_t)(j * 16 + lc) * LPAD + r0];
        #pragma unroll
        for (int i = 0; i < 4; ++i)
            #pragma unroll
            for (int j = 0; j < 4; ++j)
                acc[i][j] = __builtin_amdgcn_mfma_f32_16x16x32_bf16(af[i], bfr[j], acc[i][j], 0, 0, 0);
    }
    float* op = outP + ((size_t)slab * 256 + bh) * 4096;
    #pragma unroll
    for (int i = 0; i < 4; ++i)
        #pragma unroll
        for (int reg = 0; reg < 4; ++reg) {
            int d = i * 16 + lg * 4 + reg;
            #pragma unroll
            for (int j = 0; j < 4; ++j)
                op[d * 64 + j * 16 + lc] = acc[i][j][reg];
        }
}

// ---------------------------------------------------------------------------
// K6: x[b,h*64+k] = BN((1/8) sum_d (sum_g Mp)(sum_g Np))
// ---------------------------------------------------------------------------
__global__ __launch_bounds__(256) void xout_kernel(
    const float* __restrict__ Mp, const float* __restrict__ Np,
    const float* __restrict__ gamma, const float* __restrict__ beta,
    const float* __restrict__ mean, const float* __restrict__ var,
    float* __restrict__ outX)
{
    int bh = blockIdx.x, b = bh >> 3, h = bh & 7;
    int tid = threadIdx.x;
    int k = tid & 63, dg = tid >> 6;
    float s = 0.f;
    for (int d = dg * 16; d < dg * 16 + 16; ++d) {
        int o = d * 64 + k;
        float m = 0.f, n = 0.f;
        #pragma unroll
        for (int g = 0; g < GM; ++g) m += Mp[((size_t)g * 256 + bh) * 4096 + o];
        #pragma unroll
        for (int g = 0; g < GN; ++g) n += Np[((size_t)g * 256 + bh) * 4096 + o];
        s += m * n;
    }
    __shared__ float red[4][64];
    red[dg][k] = s;
    __syncthreads();
    if (tid < 64) {
        float x = (red[0][tid] + red[1][tid] + red[2][tid] + red[3][tid]) * 0.125f;
        int c = h * HD + tid;
        outX[(size_t)b * HID + c] =
            (x - mean[c]) * rsqrtf(var[c] + 1e-5f) * gamma[c] + beta[c];
    }
}

extern "C" void kernel_launch(void* const* d_in, const int* in_sizes, int n_in,
                              void* d_out, int out_size, void* d_ws, size_t ws_size,
                              hipStream_t stream) {
    const float* query = (const float*)d_in[0];
    const float* key   = (const float*)d_in[1];
    const float* att   = (const float*)d_in[2];
    const float* Wq  = (const float*)d_in[3];
    const float* bq  = (const float*)d_in[4];
    const float* Wk  = (const float*)d_in[5];
    const float* bk  = (const float*)d_in[6];
    const float* Wv1 = (const float*)d_in[7];
    const float* bv1 = (const float*)d_in[8];
    const float* Wv2 = (const float*)d_in[9];
    const float* bv2 = (const float*)d_in[10];
    const float* gamma = (const float*)d_in[11];
    const float* beta  = (const float*)d_in[12];
    const float* mean  = (const float*)d_in[13];
    const float* var   = (const float*)d_in[14];

    float* out    = (float*)d_out;
    float* outX   = out;             // [32,512]
    float* outIdx = out + 16384;     // [32,200] idx as float
    float* outA   = out + 22784;     // [32,200,1200]

    char* ws = (char*)d_ws;
    size_t off = 0;
    auto carve = [&](size_t bytes) {
        void* p = ws + off; off += (bytes + 255) & ~(size_t)255; return p;
    };
    int*            idxws = (int*)carve((size_t)NB * LP * 4);
    unsigned short* Wqt   = (unsigned short*)carve((size_t)HID * VD * 2);
    unsigned short* Wkt   = (unsigned short*)carve((size_t)HID * VD * 2);
    unsigned short* Wv1t  = (unsigned short*)carve((size_t)HID * VD * 2);
    unsigned short* Wv2t  = (unsigned short*)carve((size_t)HID * VD * 2);
    unsigned short* Kp    = (unsigned short*)carve((size_t)NB * LQ * HID * 2);  // 39.3 MB
    unsigned short* Qt    = (unsigned short*)carve((size_t)NB * HID * LPP * 2);
    unsigned short* Kt    = (unsigned short*)carve((size_t)NB * HID * LQP * 2);
    unsigned short* V1t   = (unsigned short*)carve((size_t)NB * HID * LPP * 2);
    unsigned short* V2t   = (unsigned short*)carve((size_t)NB * HID * LQP * 2);
    float*          pe    = (float*)carve((size_t)LQ * VD * 4);
    unsigned short* Qp    = (unsigned short*)carve((size_t)NB * LP * HID * 2);
    // Mp/Np alias Kp (dead after attnavg): GM*4MB + GN*4MB = 25.2MB <= 39.3MB
    float* Mp = (float*)Kp;
    float* Np = (float*)((char*)Kp + (size_t)GM * 256 * 4096 * 4);
    (void)ws_size; (void)in_sizes; (void)n_in; (void)out_size;

    topk_kernel<<<dim3(NB), dim3(256), 0, stream>>>(att, idxws, outIdx);
    prep_kernel<<<dim3(664), dim3(256), 0, stream>>>(
        pe, Wq, Wk, Wv1, Wv2, Wqt, Wkt, Wv1t, Wv2t);

    // all four projections: z = p*32+b, p: 0=K,1=V2,2=Q,3=V1 (p>=2 uses x<2)
    proj_kernel<<<dim3(10, 4, 128), dim3(256), 0, stream>>>(
        query, key, idxws, pe, Wqt, Wkt, Wv1t, Wv2t, bq, bk, bv1, bv2,
        Qp, Kp, Qt, Kt, V1t, V2t);

    attnavg_kernel<<<dim3(10, 2, NB), dim3(256), 0, stream>>>(Qp, Kp, outA);

    pair_kernel<<<dim3(GM + GN, 256), dim3(64), 0, stream>>>(
        Kt, V2t, Qt, V1t, Mp, Np);

    xout_kernel<<<dim3(256), dim3(256), 0, stream>>>(
        Mp, Np, gamma, beta, mean, var, outX);
}